// Round 1
// 1248.636 us; speedup vs baseline: 1.0409x; 1.0409x over previous
//
#include <hip/hip_runtime.h>
#include <hip/hip_bf16.h>

#define T_TOK  2048
#define DIMSZ  2048
#define NEXP   32
#define INTERS 1024
#define SINTER 2048
#define NTOPK  6

typedef __bf16 bf16x8 __attribute__((ext_vector_type(8)));
typedef float  f32x4  __attribute__((ext_vector_type(4)));

__device__ __forceinline__ unsigned short f2b(float f) {
    __hip_bfloat16 h = __float2bfloat16(f);
    return __builtin_bit_cast(unsigned short, h);
}

// async global->LDS, 16B per lane. LDS dest is wave-uniform base + lane*16.
__device__ __forceinline__ void gl_lds16(const unsigned short* g, unsigned short* l) {
    __builtin_amdgcn_global_load_lds(
        (const __attribute__((address_space(1))) void*)g,
        (__attribute__((address_space(3))) void*)l, 16, 0, 0);
}

// ---------------- f32 -> bf16 (grid-stride) ----------------
__global__ void cvt_f2b(const float4* __restrict__ src, ushort4* __restrict__ dst, int n4) {
    int stride = gridDim.x * blockDim.x;
    for (int i = blockIdx.x * blockDim.x + threadIdx.x; i < n4; i += stride) {
        float4 v = src[i];
        ushort4 o;
        o.x = f2b(v.x); o.y = f2b(v.y); o.z = f2b(v.z); o.w = f2b(v.w);
        dst[i] = o;
    }
}

// ---------------- gate scores: scores[T,E] = sigmoid(x @ gw^T), fp32 ----------------
#define SCT 8
#define SCK 128
__global__ __launch_bounds__(256) void gate_scores_kernel(
    const float* __restrict__ x, const float* __restrict__ gw, float* __restrict__ scores)
{
    __shared__ float xs[SCT * SCK];            // 8 x 128
    __shared__ float gs[NEXP * (SCK + 1)];     // 32 x 129 (pad: conflict-free)
    const int t0 = blockIdx.x * SCT;
    const int tid = threadIdx.x;
    const int tl = tid >> 5, e = tid & 31;
    float acc = 0.f;
    for (int k0 = 0; k0 < DIMSZ; k0 += SCK) {
        {   // xs: 1024 floats = 256 x float4
            int row = tid >> 5, d4 = tid & 31;
            *(float4*)&xs[row * SCK + d4 * 4] =
                *(const float4*)&x[(size_t)(t0 + row) * DIMSZ + k0 + d4 * 4];
        }
        #pragma unroll
        for (int i = 0; i < 4; ++i) {  // gs: 4096 floats = 256 x 4 x float4
            int lin = tid + i * 256;
            int row = lin >> 5, d4 = lin & 31;
            float4 v = *(const float4*)&gw[(size_t)row * DIMSZ + k0 + d4 * 4];
            float* dst = &gs[row * (SCK + 1) + d4 * 4];
            dst[0] = v.x; dst[1] = v.y; dst[2] = v.z; dst[3] = v.w;
        }
        __syncthreads();
        #pragma unroll 8
        for (int d = 0; d < SCK; ++d)
            acc += xs[tl * SCK + d] * gs[e * (SCK + 1) + d];
        __syncthreads();
    }
    scores[(size_t)(t0 + tl) * NEXP + e] = 1.f / (1.f + expf(-acc));
}

// ---------------- top-k routing (one thread per token) ----------------
__global__ __launch_bounds__(256) void topk_kernel(
    const float* __restrict__ scores,
    int* __restrict__ counts, int* __restrict__ toklist, float* __restrict__ wgts)
{
    int t = blockIdx.x * 256 + threadIdx.x;
    if (t >= T_TOK) return;
    float sc[NEXP];
    #pragma unroll
    for (int e = 0; e < NEXP; ++e) sc[e] = scores[(size_t)t * NEXP + e];

    float gsc[8];
    #pragma unroll
    for (int g = 0; g < 8; ++g) {
        float m = sc[4 * g];
        #pragma unroll
        for (int j = 1; j < 4; ++j) m = fmaxf(m, sc[4 * g + j]);
        gsc[g] = m;
    }
    bool gsel[8] = {false, false, false, false, false, false, false, false};
    for (int it = 0; it < 4; ++it) {
        int bi = -1; float bv = -1e30f;
        #pragma unroll
        for (int g = 0; g < 8; ++g)
            if (!gsel[g] && gsc[g] > bv) { bv = gsc[g]; bi = g; }
        gsel[bi] = true;
    }
    bool esel[NEXP];
    #pragma unroll
    for (int e = 0; e < NEXP; ++e) esel[e] = false;
    int   idx[NTOPK];
    float w[NTOPK];
    float sum = 0.f;
    for (int it = 0; it < NTOPK; ++it) {
        int bi = -1; float bv = -1e30f;
        #pragma unroll
        for (int e = 0; e < NEXP; ++e) {
            if (!gsel[e >> 2] || esel[e]) continue;
            if (sc[e] > bv) { bv = sc[e]; bi = e; }
        }
        esel[bi] = true; idx[it] = bi; w[it] = bv; sum += bv;
    }
    float scale = 2.5f / sum;
    for (int k = 0; k < NTOPK; ++k) {
        int e = idx[k];
        int s = atomicAdd(&counts[e], 1);
        toklist[e * T_TOK + s] = (t << 3) | k;
        wgts[e * T_TOK + s]   = w[k] * scale;
    }
}

// ---------------- fused fc1: H = silu(A@B1^T) * (A@B2^T), bf16 out ----------------
// WB=true: B tensors are pre-converted bf16; staging via global_load_lds into
// linear LDS (LDK=64) with T2 XOR-swizzle applied BOTH sides:
//   store: lane fetches global 16B-slot ((l&7) ^ (l>>3)) of its row  (src pre-swizzle)
//   read : fragment slot (quad+4*kh) found at LDS slot (slot ^ (row&7))
// WB=false: original fp32 path (padded LDK=72, VGPR staging + f2b).
template <bool GROUPED, bool WB>
__global__ __launch_bounds__(256, 2) void fc1_fused(
    const unsigned short* __restrict__ A,
    const void* __restrict__ B1t, const void* __restrict__ B2t,
    unsigned short* __restrict__ H, int N, int K, int M_fixed,
    const int* __restrict__ counts, const int* __restrict__ toklist)
{
    constexpr int BM = 128, BN = 128, BK = 64;
    constexpr int LDK = WB ? 64 : 72;
    __shared__ unsigned short As[BM * LDK];
    __shared__ unsigned short B1s[BN * LDK];
    __shared__ unsigned short B2s[BN * LDK];
    __shared__ int aRowS[BM];
    __shared__ int cRowS[BM];

    const int tid = threadIdx.x;
    const int e  = blockIdx.z;
    const int m0 = blockIdx.y * BM;
    const int n0 = blockIdx.x * BN;

    int M;
    size_t eoff = 0;
    if constexpr (GROUPED) {
        M = counts[e];
        if (m0 >= M) return;
        eoff = (size_t)e * N * K;
    } else {
        M = M_fixed;
    }
    const float* B1f = (const float*)B1t + eoff;
    const float* B2f = (const float*)B2t + eoff;
    const unsigned short* B1h = (const unsigned short*)B1t + eoff;
    const unsigned short* B2h = (const unsigned short*)B2t + eoff;

    if (tid < BM) {
        int r = m0 + tid;
        if constexpr (GROUPED) {
            if (r < M) {
                int ent = toklist[e * T_TOK + r];
                int t = ent >> 3, k = ent & 7;
                aRowS[tid] = t; cRowS[tid] = t * NTOPK + k;
            } else { aRowS[tid] = 0; cRowS[tid] = -1; }
        } else {
            aRowS[tid] = r; cRowS[tid] = (r < M) ? r : -1;
        }
    }
    __syncthreads();

    f32x4 acc1[4][4] = {};
    f32x4 acc2[4][4] = {};

    const int wave = tid >> 6;
    const int lane = tid & 63;
    const int wm = (wave >> 1) * 64;
    const int wn = (wave & 1) * 64;
    const int lm = lane & 15;
    const int quad = lane >> 4;

    // hoisted per-lane source pointers for the gl_lds path (4 chunks of 8 rows each)
    const unsigned short *aP[4], *b1P[4], *b2P[4];
    if constexpr (WB) {
        const int l8 = lane >> 3;                 // row within chunk (0..7)
        const int sg = (lane & 7) ^ l8;           // pre-swizzled 16B slot within row
        #pragma unroll
        for (int i = 0; i < 4; ++i) {
            const int c = wave * 4 + i;           // chunk 0..15, rows 8c..8c+7
            const int r = c * 8 + l8;
            aP[i]  = A   + (size_t)aRowS[r] * K + sg * 8;
            b1P[i] = B1h + (size_t)(n0 + r) * K + sg * 8;
            b2P[i] = B2h + (size_t)(n0 + r) * K + sg * 8;
        }
    }

    for (int k0 = 0; k0 < K; k0 += BK) {
        if constexpr (WB) {
            #pragma unroll
            for (int i = 0; i < 4; ++i) {
                const int c = wave * 4 + i;
                gl_lds16(aP[i]  + k0, &As [c * 512]);
                gl_lds16(b1P[i] + k0, &B1s[c * 512]);
                gl_lds16(b2P[i] + k0, &B2s[c * 512]);
            }
        } else {
            #pragma unroll
            for (int i = 0; i < 4; ++i) {
                int lin = tid + i * 256;
                int row = lin >> 3, cq = lin & 7;
                const unsigned short* srcp = A + (size_t)aRowS[row] * K + k0 + cq * 8;
                *(float4*)&As[row * LDK + cq * 8] = *(const float4*)srcp;
            }
            #pragma unroll
            for (int i = 0; i < 8; ++i) {
                int lin = tid + i * 256;
                int row = lin >> 4, cq = lin & 15;
                size_t boff = (size_t)(n0 + row) * K + k0 + cq * 4;
                float4 v1 = *(const float4*)(B1f + boff);
                float4 v2 = *(const float4*)(B2f + boff);
                ushort4 o1, o2;
                o1.x = f2b(v1.x); o1.y = f2b(v1.y); o1.z = f2b(v1.z); o1.w = f2b(v1.w);
                o2.x = f2b(v2.x); o2.y = f2b(v2.y); o2.z = f2b(v2.z); o2.w = f2b(v2.w);
                *(ushort4*)&B1s[row * LDK + cq * 4] = o1;
                *(ushort4*)&B2s[row * LDK + cq * 4] = o2;
            }
        }
        __syncthreads();   // drains vmcnt(0) before barrier -> gl_lds data visible
        #pragma unroll
        for (int kh = 0; kh < 2; ++kh) {
            const int soff = WB ? ((((kh << 2) | quad) ^ (lm & 7)) << 3)
                                : (kh * 32 + quad * 8);
            bf16x8 af[4], bf1[4], bf2[4];
            #pragma unroll
            for (int ti = 0; ti < 4; ++ti)
                af[ti] = *(const bf16x8*)&As[(wm + ti * 16 + lm) * LDK + soff];
            #pragma unroll
            for (int tj = 0; tj < 4; ++tj) {
                bf1[tj] = *(const bf16x8*)&B1s[(wn + tj * 16 + lm) * LDK + soff];
                bf2[tj] = *(const bf16x8*)&B2s[(wn + tj * 16 + lm) * LDK + soff];
            }
            #pragma unroll
            for (int ti = 0; ti < 4; ++ti)
                #pragma unroll
                for (int tj = 0; tj < 4; ++tj) {
                    acc1[ti][tj] = __builtin_amdgcn_mfma_f32_16x16x32_bf16(
                        af[ti], bf1[tj], acc1[ti][tj], 0, 0, 0);
                    acc2[ti][tj] = __builtin_amdgcn_mfma_f32_16x16x32_bf16(
                        af[ti], bf2[tj], acc2[ti][tj], 0, 0, 0);
                }
        }
        __syncthreads();
    }

    #pragma unroll
    for (int ti = 0; ti < 4; ++ti) {
        #pragma unroll
        for (int r = 0; r < 4; ++r) {
            int lrow = wm + ti * 16 + quad * 4 + r;
            int cr = cRowS[lrow];
            if (cr < 0) continue;
            #pragma unroll
            for (int tj = 0; tj < 4; ++tj) {
                int nn = n0 + wn + tj * 16 + lm;
                float g = acc1[ti][tj][r];
                float u = acc2[ti][tj][r];
                float h = g / (1.f + expf(-g)) * u;
                H[(size_t)cr * N + nn] = f2b(h);
            }
        }
    }
}

// ---------------- fc2 GEMM: C[M,N] = A[M,K] @ Bt[N,K]^T ----------------
#define SHARED_F32  1  // overwrite f32 C (d_out)
#define GROUP_FC2   3  // atomicAdd wgt*acc into f32 C row t

template <int MODE, bool WB>
__global__ __launch_bounds__(256, 2) void gemm_bt(
    const unsigned short* __restrict__ A, const void* __restrict__ Bt,
    float* __restrict__ Cf, int N, int K, int M_fixed,
    const int* __restrict__ counts, const int* __restrict__ toklist,
    const float* __restrict__ wgts)
{
    constexpr int BM = 128, BN = 128, BK = 64;
    constexpr int LDK = WB ? 64 : 72;
    __shared__ unsigned short As[BM * LDK];
    __shared__ unsigned short Bs[BN * LDK];
    __shared__ int   aRowS[BM];
    __shared__ int   cRowS[BM];
    __shared__ float cWS[BM];

    const int tid = threadIdx.x;
    const int e  = blockIdx.z;
    const int m0 = blockIdx.y * BM;
    const int n0 = blockIdx.x * BN;

    int M;
    size_t eoff = 0;
    if constexpr (MODE == GROUP_FC2) {
        M = counts[e];
        if (m0 >= M) return;
        eoff = (size_t)e * N * K;
    } else {
        M = M_fixed;
    }
    const float* Bf = (const float*)Bt + eoff;
    const unsigned short* Bh = (const unsigned short*)Bt + eoff;

    if (tid < BM) {
        int r = m0 + tid;
        if constexpr (MODE == GROUP_FC2) {
            if (r < M) {
                int ent = toklist[e * T_TOK + r];
                int t = ent >> 3, k = ent & 7;
                aRowS[tid] = t * NTOPK + k; cRowS[tid] = t;
                cWS[tid] = wgts[e * T_TOK + r];
            } else { aRowS[tid] = 0; cRowS[tid] = -1; cWS[tid] = 0.f; }
        } else {
            aRowS[tid] = r; cRowS[tid] = (r < M) ? r : -1; cWS[tid] = 0.f;
        }
    }
    __syncthreads();

    f32x4 acc[4][4] = {};

    const int wave = tid >> 6;
    const int lane = tid & 63;
    const int wm = (wave >> 1) * 64;
    const int wn = (wave & 1) * 64;
    const int lm = lane & 15;
    const int quad = lane >> 4;

    const unsigned short *aP[4], *bP[4];
    if constexpr (WB) {
        const int l8 = lane >> 3;
        const int sg = (lane & 7) ^ l8;
        #pragma unroll
        for (int i = 0; i < 4; ++i) {
            const int c = wave * 4 + i;
            const int r = c * 8 + l8;
            aP[i] = A  + (size_t)aRowS[r] * K + sg * 8;
            bP[i] = Bh + (size_t)(n0 + r) * K + sg * 8;
        }
    }

    for (int k0 = 0; k0 < K; k0 += BK) {
        if constexpr (WB) {
            #pragma unroll
            for (int i = 0; i < 4; ++i) {
                const int c = wave * 4 + i;
                gl_lds16(aP[i] + k0, &As[c * 512]);
                gl_lds16(bP[i] + k0, &Bs[c * 512]);
            }
        } else {
            #pragma unroll
            for (int i = 0; i < 4; ++i) {
                int lin = tid + i * 256;
                int row = lin >> 3, cq = lin & 7;
                const unsigned short* srcp = A + (size_t)aRowS[row] * K + k0 + cq * 8;
                *(float4*)&As[row * LDK + cq * 8] = *(const float4*)srcp;
            }
            #pragma unroll
            for (int i = 0; i < 8; ++i) {
                int lin = tid + i * 256;
                int row = lin >> 4, cq = lin & 15;
                const float* srcp = Bf + (size_t)(n0 + row) * K + k0 + cq * 4;
                float4 v = *(const float4*)srcp;
                ushort4 o;
                o.x = f2b(v.x); o.y = f2b(v.y); o.z = f2b(v.z); o.w = f2b(v.w);
                *(ushort4*)&Bs[row * LDK + cq * 4] = o;
            }
        }
        __syncthreads();
        #pragma unroll
        for (int kh = 0; kh < 2; ++kh) {
            const int soff = WB ? ((((kh << 2) | quad) ^ (lm & 7)) << 3)
                                : (kh * 32 + quad * 8);
            bf16x8 af[4], bfr[4];
            #pragma unroll
            for (int ti = 0; ti < 4; ++ti)
                af[ti] = *(const bf16x8*)&As[(wm + ti * 16 + lm) * LDK + soff];
            #pragma unroll
            for (int tj = 0; tj < 4; ++tj)
                bfr[tj] = *(const bf16x8*)&Bs[(wn + tj * 16 + lm) * LDK + soff];
            #pragma unroll
            for (int ti = 0; ti < 4; ++ti)
                #pragma unroll
                for (int tj = 0; tj < 4; ++tj)
                    acc[ti][tj] = __builtin_amdgcn_mfma_f32_16x16x32_bf16(
                        af[ti], bfr[tj], acc[ti][tj], 0, 0, 0);
        }
        __syncthreads();
    }

    #pragma unroll
    for (int ti = 0; ti < 4; ++ti) {
        #pragma unroll
        for (int r = 0; r < 4; ++r) {
            int lrow = wm + ti * 16 + quad * 4 + r;
            int cr = cRowS[lrow];
            if (cr < 0) continue;
            #pragma unroll
            for (int tj = 0; tj < 4; ++tj) {
                int nn = n0 + wn + tj * 16 + lm;
                float v = acc[ti][tj][r];
                if constexpr (MODE == SHARED_F32)
                    Cf[(size_t)cr * N + nn] = v;
                else
                    atomicAdd(&Cf[(size_t)cr * N + nn], v * cWS[lrow]);
            }
        }
    }
}

extern "C" void kernel_launch(void* const* d_in, const int* in_sizes, int n_in,
                              void* d_out, int out_size, void* d_ws, size_t ws_size,
                              hipStream_t stream)
{
    const float* x   = (const float*)d_in[0];
    const float* gw  = (const float*)d_in[1];
    const float* w11 = (const float*)d_in[2];
    const float* w33 = (const float*)d_in[3];
    const float* w22 = (const float*)d_in[4];
    const float* sw1 = (const float*)d_in[5];
    const float* sw2 = (const float*)d_in[6];
    const float* sw3 = (const float*)d_in[7];
    float* out = (float*)d_out;

    char* ws = (char*)d_ws;
    size_t off = 0;
    auto alloc = [&](size_t b) { void* p = ws + off; off = (off + b + 255) & ~(size_t)255; return p; };
    int*            counts  = (int*)alloc(NEXP * 4);
    int*            toklist = (int*)alloc((size_t)NEXP * T_TOK * 4);
    float*          wgts    = (float*)alloc((size_t)NEXP * T_TOK * 4);
    float*          scores  = (float*)alloc((size_t)T_TOK * NEXP * 4);
    unsigned short* xb      = (unsigned short*)alloc((size_t)T_TOK * DIMSZ * 2);
    unsigned short* h       = (unsigned short*)alloc((size_t)T_TOK * NTOPK * INTERS * 2);
    unsigned short* hs      = (unsigned short*)alloc((size_t)T_TOK * SINTER * 2);

    // bf16 weight mirrors (fast path) -- only if workspace is large enough
    const size_t nW = (size_t)NEXP * INTERS * DIMSZ;   // 67.1M elems each of w11/w33/w22
    const size_t nS = (size_t)SINTER * DIMSZ;          // 4.19M elems each of sw1/sw3/sw2
    const size_t wbytes = 3 * (nW * 2) + 3 * (nS * 2) + 6 * 256;
    const bool WB = (off + wbytes) <= ws_size;
    unsigned short *w11b = nullptr, *w33b = nullptr, *w22b = nullptr;
    unsigned short *sw1b = nullptr, *sw3b = nullptr, *sw2b = nullptr;
    if (WB) {
        w11b = (unsigned short*)alloc(nW * 2);
        w33b = (unsigned short*)alloc(nW * 2);
        w22b = (unsigned short*)alloc(nW * 2);
        sw1b = (unsigned short*)alloc(nS * 2);
        sw3b = (unsigned short*)alloc(nS * 2);
        sw2b = (unsigned short*)alloc(nS * 2);
    }

    hipMemsetAsync(counts, 0, NEXP * 4, stream);

    int n4x = T_TOK * DIMSZ / 4;
    cvt_f2b<<<4096, 256, 0, stream>>>((const float4*)x, (ushort4*)xb, n4x);
    if (WB) {
        cvt_f2b<<<4096, 256, 0, stream>>>((const float4*)w11, (ushort4*)w11b, (int)(nW / 4));
        cvt_f2b<<<4096, 256, 0, stream>>>((const float4*)w33, (ushort4*)w33b, (int)(nW / 4));
        cvt_f2b<<<4096, 256, 0, stream>>>((const float4*)w22, (ushort4*)w22b, (int)(nW / 4));
        cvt_f2b<<<2048, 256, 0, stream>>>((const float4*)sw1, (ushort4*)sw1b, (int)(nS / 4));
        cvt_f2b<<<2048, 256, 0, stream>>>((const float4*)sw3, (ushort4*)sw3b, (int)(nS / 4));
        cvt_f2b<<<2048, 256, 0, stream>>>((const float4*)sw2, (ushort4*)sw2b, (int)(nS / 4));
    }

    gate_scores_kernel<<<T_TOK / SCT, 256, 0, stream>>>(x, gw, scores);
    topk_kernel<<<(T_TOK + 255) / 256, 256, 0, stream>>>(scores, counts, toklist, wgts);

    if (WB) {
        fc1_fused<false, true><<<dim3(SINTER / 128, T_TOK / 128, 1), 256, 0, stream>>>(
            xb, sw1b, sw3b, hs, SINTER, DIMSZ, T_TOK, nullptr, nullptr);
        gemm_bt<SHARED_F32, true><<<dim3(DIMSZ / 128, T_TOK / 128, 1), 256, 0, stream>>>(
            hs, sw2b, out, DIMSZ, SINTER, T_TOK, nullptr, nullptr, nullptr);
        fc1_fused<true, true><<<dim3(INTERS / 128, T_TOK / 128, NEXP), 256, 0, stream>>>(
            xb, w11b, w33b, h, INTERS, DIMSZ, 0, counts, toklist);
        gemm_bt<GROUP_FC2, true><<<dim3(DIMSZ / 128, T_TOK / 128, NEXP), 256, 0, stream>>>(
            h, w22b, out, DIMSZ, INTERS, 0, counts, toklist, wgts);
    } else {
        fc1_fused<false, false><<<dim3(SINTER / 128, T_TOK / 128, 1), 256, 0, stream>>>(
            xb, sw1, sw3, hs, SINTER, DIMSZ, T_TOK, nullptr, nullptr);
        gemm_bt<SHARED_F32, false><<<dim3(DIMSZ / 128, T_TOK / 128, 1), 256, 0, stream>>>(
            hs, sw2, out, DIMSZ, SINTER, T_TOK, nullptr, nullptr, nullptr);
        fc1_fused<true, false><<<dim3(INTERS / 128, T_TOK / 128, NEXP), 256, 0, stream>>>(
            xb, w11, w33, h, INTERS, DIMSZ, 0, counts, toklist);
        gemm_bt<GROUP_FC2, false><<<dim3(DIMSZ / 128, T_TOK / 128, NEXP), 256, 0, stream>>>(
            h, w22, out, DIMSZ, INTERS, 0, counts, toklist, wgts);
    }
}

// Round 2
// 1242.727 us; speedup vs baseline: 1.0459x; 1.0048x over previous
//
#include <hip/hip_runtime.h>
#include <hip/hip_bf16.h>

#define T_TOK  2048
#define DIMSZ  2048
#define NEXP   32
#define INTERS 1024
#define SINTER 2048
#define NTOPK  6

typedef __bf16 bf16x8 __attribute__((ext_vector_type(8)));
typedef float  f32x4  __attribute__((ext_vector_type(4)));

__device__ __forceinline__ unsigned short f2b(float f) {
    __hip_bfloat16 h = __float2bfloat16(f);
    return __builtin_bit_cast(unsigned short, h);
}

// async global->LDS, 16B per lane. LDS dest is wave-uniform base + lane*16.
__device__ __forceinline__ void gl_lds16(const unsigned short* g, unsigned short* l) {
    __builtin_amdgcn_global_load_lds(
        (const __attribute__((address_space(1))) void*)g,
        (__attribute__((address_space(3))) void*)l, 16, 0, 0);
}

// ---------------- f32 -> bf16 (grid-stride) ----------------
__global__ void cvt_f2b(const float4* __restrict__ src, ushort4* __restrict__ dst, int n4) {
    int stride = gridDim.x * blockDim.x;
    for (int i = blockIdx.x * blockDim.x + threadIdx.x; i < n4; i += stride) {
        float4 v = src[i];
        ushort4 o;
        o.x = f2b(v.x); o.y = f2b(v.y); o.z = f2b(v.z); o.w = f2b(v.w);
        dst[i] = o;
    }
}

// ---------------- gate scores: scores[T,E] = sigmoid(x @ gw^T), fp32 ----------------
#define SCT 8
#define SCK 128
__global__ __launch_bounds__(256) void gate_scores_kernel(
    const float* __restrict__ x, const float* __restrict__ gw, float* __restrict__ scores)
{
    __shared__ float xs[SCT * SCK];            // 8 x 128
    __shared__ float gs[NEXP * (SCK + 1)];     // 32 x 129 (pad: conflict-free)
    const int t0 = blockIdx.x * SCT;
    const int tid = threadIdx.x;
    const int tl = tid >> 5, e = tid & 31;
    float acc = 0.f;
    for (int k0 = 0; k0 < DIMSZ; k0 += SCK) {
        {   // xs: 1024 floats = 256 x float4
            int row = tid >> 5, d4 = tid & 31;
            *(float4*)&xs[row * SCK + d4 * 4] =
                *(const float4*)&x[(size_t)(t0 + row) * DIMSZ + k0 + d4 * 4];
        }
        #pragma unroll
        for (int i = 0; i < 4; ++i) {  // gs: 4096 floats = 256 x 4 x float4
            int lin = tid + i * 256;
            int row = lin >> 5, d4 = lin & 31;
            float4 v = *(const float4*)&gw[(size_t)row * DIMSZ + k0 + d4 * 4];
            float* dst = &gs[row * (SCK + 1) + d4 * 4];
            dst[0] = v.x; dst[1] = v.y; dst[2] = v.z; dst[3] = v.w;
        }
        __syncthreads();
        #pragma unroll 8
        for (int d = 0; d < SCK; ++d)
            acc += xs[tl * SCK + d] * gs[e * (SCK + 1) + d];
        __syncthreads();
    }
    scores[(size_t)(t0 + tl) * NEXP + e] = 1.f / (1.f + expf(-acc));
}

// ---------------- top-k routing (one thread per token) ----------------
__global__ __launch_bounds__(256) void topk_kernel(
    const float* __restrict__ scores,
    int* __restrict__ counts, int* __restrict__ toklist, float* __restrict__ wgts)
{
    int t = blockIdx.x * 256 + threadIdx.x;
    if (t >= T_TOK) return;
    float sc[NEXP];
    #pragma unroll
    for (int e = 0; e < NEXP; ++e) sc[e] = scores[(size_t)t * NEXP + e];

    float gsc[8];
    #pragma unroll
    for (int g = 0; g < 8; ++g) {
        float m = sc[4 * g];
        #pragma unroll
        for (int j = 1; j < 4; ++j) m = fmaxf(m, sc[4 * g + j]);
        gsc[g] = m;
    }
    bool gsel[8] = {false, false, false, false, false, false, false, false};
    for (int it = 0; it < 4; ++it) {
        int bi = -1; float bv = -1e30f;
        #pragma unroll
        for (int g = 0; g < 8; ++g)
            if (!gsel[g] && gsc[g] > bv) { bv = gsc[g]; bi = g; }
        gsel[bi] = true;
    }
    bool esel[NEXP];
    #pragma unroll
    for (int e = 0; e < NEXP; ++e) esel[e] = false;
    int   idx[NTOPK];
    float w[NTOPK];
    float sum = 0.f;
    for (int it = 0; it < NTOPK; ++it) {
        int bi = -1; float bv = -1e30f;
        #pragma unroll
        for (int e = 0; e < NEXP; ++e) {
            if (!gsel[e >> 2] || esel[e]) continue;
            if (sc[e] > bv) { bv = sc[e]; bi = e; }
        }
        esel[bi] = true; idx[it] = bi; w[it] = bv; sum += bv;
    }
    float scale = 2.5f / sum;
    for (int k = 0; k < NTOPK; ++k) {
        int e = idx[k];
        int s = atomicAdd(&counts[e], 1);
        toklist[e * T_TOK + s] = (t << 3) | k;
        wgts[e * T_TOK + s]   = w[k] * scale;
    }
}

// ---------------- fused fc1: H = silu(A@B1^T) * (A@B2^T), bf16 out ----------------
template <bool GROUPED, bool WB>
__global__ __launch_bounds__(256, 2) void fc1_fused(
    const unsigned short* __restrict__ A,
    const void* __restrict__ B1t, const void* __restrict__ B2t,
    unsigned short* __restrict__ H, int N, int K, int M_fixed,
    const int* __restrict__ counts, const int* __restrict__ toklist)
{
    constexpr int BM = 128, BN = 128, BK = 64;
    constexpr int LDK = WB ? 64 : 72;
    __shared__ unsigned short As[BM * LDK];
    __shared__ unsigned short B1s[BN * LDK];
    __shared__ unsigned short B2s[BN * LDK];
    __shared__ int aRowS[BM];
    __shared__ int cRowS[BM];

    const int tid = threadIdx.x;
    const int e  = blockIdx.z;
    const int m0 = blockIdx.y * BM;
    const int n0 = blockIdx.x * BN;

    int M;
    size_t eoff = 0;
    if constexpr (GROUPED) {
        M = counts[e];
        if (m0 >= M) return;
        eoff = (size_t)e * N * K;
    } else {
        M = M_fixed;
    }
    const float* B1f = (const float*)B1t + eoff;
    const float* B2f = (const float*)B2t + eoff;
    const unsigned short* B1h = (const unsigned short*)B1t + eoff;
    const unsigned short* B2h = (const unsigned short*)B2t + eoff;

    if (tid < BM) {
        int r = m0 + tid;
        if constexpr (GROUPED) {
            if (r < M) {
                int ent = toklist[e * T_TOK + r];
                int t = ent >> 3, k = ent & 7;
                aRowS[tid] = t; cRowS[tid] = t * NTOPK + k;
            } else { aRowS[tid] = 0; cRowS[tid] = -1; }
        } else {
            aRowS[tid] = r; cRowS[tid] = (r < M) ? r : -1;
        }
    }
    __syncthreads();

    f32x4 acc1[4][4] = {};
    f32x4 acc2[4][4] = {};

    const int wave = tid >> 6;
    const int lane = tid & 63;
    const int wm = (wave >> 1) * 64;
    const int wn = (wave & 1) * 64;
    const int lm = lane & 15;
    const int quad = lane >> 4;

    // hoisted per-lane source pointers for the gl_lds path (4 chunks of 8 rows each)
    const unsigned short *aP[4], *b1P[4], *b2P[4];
    if constexpr (WB) {
        const int l8 = lane >> 3;                 // row within chunk (0..7)
        const int sg = (lane & 7) ^ l8;           // pre-swizzled 16B slot within row
        #pragma unroll
        for (int i = 0; i < 4; ++i) {
            const int c = wave * 4 + i;           // chunk 0..15, rows 8c..8c+7
            const int r = c * 8 + l8;
            aP[i]  = A   + (size_t)aRowS[r] * K + sg * 8;
            b1P[i] = B1h + (size_t)(n0 + r) * K + sg * 8;
            b2P[i] = B2h + (size_t)(n0 + r) * K + sg * 8;
        }
    }

    for (int k0 = 0; k0 < K; k0 += BK) {
        if constexpr (WB) {
            #pragma unroll
            for (int i = 0; i < 4; ++i) {
                const int c = wave * 4 + i;
                gl_lds16(aP[i]  + k0, &As [c * 512]);
                gl_lds16(b1P[i] + k0, &B1s[c * 512]);
                gl_lds16(b2P[i] + k0, &B2s[c * 512]);
            }
        } else {
            #pragma unroll
            for (int i = 0; i < 4; ++i) {
                int lin = tid + i * 256;
                int row = lin >> 3, cq = lin & 7;
                const unsigned short* srcp = A + (size_t)aRowS[row] * K + k0 + cq * 8;
                *(float4*)&As[row * LDK + cq * 8] = *(const float4*)srcp;
            }
            #pragma unroll
            for (int i = 0; i < 8; ++i) {
                int lin = tid + i * 256;
                int row = lin >> 4, cq = lin & 15;
                size_t boff = (size_t)(n0 + row) * K + k0 + cq * 4;
                float4 v1 = *(const float4*)(B1f + boff);
                float4 v2 = *(const float4*)(B2f + boff);
                ushort4 o1, o2;
                o1.x = f2b(v1.x); o1.y = f2b(v1.y); o1.z = f2b(v1.z); o1.w = f2b(v1.w);
                o2.x = f2b(v2.x); o2.y = f2b(v2.y); o2.z = f2b(v2.z); o2.w = f2b(v2.w);
                *(ushort4*)&B1s[row * LDK + cq * 4] = o1;
                *(ushort4*)&B2s[row * LDK + cq * 4] = o2;
            }
        }
        __syncthreads();   // drains vmcnt(0) before barrier -> gl_lds data visible
        #pragma unroll
        for (int kh = 0; kh < 2; ++kh) {
            const int soff = WB ? ((((kh << 2) | quad) ^ (lm & 7)) << 3)
                                : (kh * 32 + quad * 8);
            bf16x8 af[4], bf1[4], bf2[4];
            #pragma unroll
            for (int ti = 0; ti < 4; ++ti)
                af[ti] = *(const bf16x8*)&As[(wm + ti * 16 + lm) * LDK + soff];
            #pragma unroll
            for (int tj = 0; tj < 4; ++tj) {
                bf1[tj] = *(const bf16x8*)&B1s[(wn + tj * 16 + lm) * LDK + soff];
                bf2[tj] = *(const bf16x8*)&B2s[(wn + tj * 16 + lm) * LDK + soff];
            }
            #pragma unroll
            for (int ti = 0; ti < 4; ++ti)
                #pragma unroll
                for (int tj = 0; tj < 4; ++tj) {
                    acc1[ti][tj] = __builtin_amdgcn_mfma_f32_16x16x32_bf16(
                        af[ti], bf1[tj], acc1[ti][tj], 0, 0, 0);
                    acc2[ti][tj] = __builtin_amdgcn_mfma_f32_16x16x32_bf16(
                        af[ti], bf2[tj], acc2[ti][tj], 0, 0, 0);
                }
        }
        __syncthreads();
    }

    #pragma unroll
    for (int ti = 0; ti < 4; ++ti) {
        #pragma unroll
        for (int r = 0; r < 4; ++r) {
            int lrow = wm + ti * 16 + quad * 4 + r;
            int cr = cRowS[lrow];
            if (cr < 0) continue;
            #pragma unroll
            for (int tj = 0; tj < 4; ++tj) {
                int nn = n0 + wn + tj * 16 + lm;
                float g = acc1[ti][tj][r];
                float u = acc2[ti][tj][r];
                float h = g / (1.f + expf(-g)) * u;
                H[(size_t)cr * N + nn] = f2b(h);
            }
        }
    }
}

// ---------------- fc2 GEMM: C[M,N] = A[M,K] @ Bt[N,K]^T ----------------
#define SHARED_F32   1  // overwrite f32 C (d_out)
#define GROUP_FC2    3  // atomicAdd wgt*acc into f32 C row t          (fallback)
#define GROUP_DENSE  4  // plain store wgt*acc into f32 yexp row t*6+k (fast path)

template <int MODE, bool WB>
__global__ __launch_bounds__(256, 2) void gemm_bt(
    const unsigned short* __restrict__ A, const void* __restrict__ Bt,
    float* __restrict__ Cf, int N, int K, int M_fixed,
    const int* __restrict__ counts, const int* __restrict__ toklist,
    const float* __restrict__ wgts)
{
    constexpr int BM = 128, BN = 128, BK = 64;
    constexpr int LDK = WB ? 64 : 72;
    constexpr bool GRP = (MODE == GROUP_FC2 || MODE == GROUP_DENSE);
    __shared__ unsigned short As[BM * LDK];
    __shared__ unsigned short Bs[BN * LDK];
    __shared__ int   aRowS[BM];
    __shared__ int   cRowS[BM];
    __shared__ float cWS[BM];

    const int tid = threadIdx.x;
    const int e  = blockIdx.z;
    const int m0 = blockIdx.y * BM;
    const int n0 = blockIdx.x * BN;

    int M;
    size_t eoff = 0;
    if constexpr (GRP) {
        M = counts[e];
        if (m0 >= M) return;
        eoff = (size_t)e * N * K;
    } else {
        M = M_fixed;
    }
    const float* Bf = (const float*)Bt + eoff;
    const unsigned short* Bh = (const unsigned short*)Bt + eoff;

    if (tid < BM) {
        int r = m0 + tid;
        if constexpr (GRP) {
            if (r < M) {
                int ent = toklist[e * T_TOK + r];
                int t = ent >> 3, k = ent & 7;
                aRowS[tid] = t * NTOPK + k;
                cRowS[tid] = (MODE == GROUP_DENSE) ? (t * NTOPK + k) : t;
                cWS[tid] = wgts[e * T_TOK + r];
            } else { aRowS[tid] = 0; cRowS[tid] = -1; cWS[tid] = 0.f; }
        } else {
            aRowS[tid] = r; cRowS[tid] = (r < M) ? r : -1; cWS[tid] = 0.f;
        }
    }
    __syncthreads();

    f32x4 acc[4][4] = {};

    const int wave = tid >> 6;
    const int lane = tid & 63;
    const int wm = (wave >> 1) * 64;
    const int wn = (wave & 1) * 64;
    const int lm = lane & 15;
    const int quad = lane >> 4;

    const unsigned short *aP[4], *bP[4];
    if constexpr (WB) {
        const int l8 = lane >> 3;
        const int sg = (lane & 7) ^ l8;
        #pragma unroll
        for (int i = 0; i < 4; ++i) {
            const int c = wave * 4 + i;
            const int r = c * 8 + l8;
            aP[i] = A  + (size_t)aRowS[r] * K + sg * 8;
            bP[i] = Bh + (size_t)(n0 + r) * K + sg * 8;
        }
    }

    for (int k0 = 0; k0 < K; k0 += BK) {
        if constexpr (WB) {
            #pragma unroll
            for (int i = 0; i < 4; ++i) {
                const int c = wave * 4 + i;
                gl_lds16(aP[i] + k0, &As[c * 512]);
                gl_lds16(bP[i] + k0, &Bs[c * 512]);
            }
        } else {
            #pragma unroll
            for (int i = 0; i < 4; ++i) {
                int lin = tid + i * 256;
                int row = lin >> 3, cq = lin & 7;
                const unsigned short* srcp = A + (size_t)aRowS[row] * K + k0 + cq * 8;
                *(float4*)&As[row * LDK + cq * 8] = *(const float4*)srcp;
            }
            #pragma unroll
            for (int i = 0; i < 8; ++i) {
                int lin = tid + i * 256;
                int row = lin >> 4, cq = lin & 15;
                const float* srcp = Bf + (size_t)(n0 + row) * K + k0 + cq * 4;
                float4 v = *(const float4*)srcp;
                ushort4 o;
                o.x = f2b(v.x); o.y = f2b(v.y); o.z = f2b(v.z); o.w = f2b(v.w);
                *(ushort4*)&Bs[row * LDK + cq * 4] = o;
            }
        }
        __syncthreads();
        #pragma unroll
        for (int kh = 0; kh < 2; ++kh) {
            const int soff = WB ? ((((kh << 2) | quad) ^ (lm & 7)) << 3)
                                : (kh * 32 + quad * 8);
            bf16x8 af[4], bfr[4];
            #pragma unroll
            for (int ti = 0; ti < 4; ++ti)
                af[ti] = *(const bf16x8*)&As[(wm + ti * 16 + lm) * LDK + soff];
            #pragma unroll
            for (int tj = 0; tj < 4; ++tj)
                bfr[tj] = *(const bf16x8*)&Bs[(wn + tj * 16 + lm) * LDK + soff];
            #pragma unroll
            for (int ti = 0; ti < 4; ++ti)
                #pragma unroll
                for (int tj = 0; tj < 4; ++tj)
                    acc[ti][tj] = __builtin_amdgcn_mfma_f32_16x16x32_bf16(
                        af[ti], bfr[tj], acc[ti][tj], 0, 0, 0);
        }
        __syncthreads();
    }

    #pragma unroll
    for (int ti = 0; ti < 4; ++ti) {
        #pragma unroll
        for (int r = 0; r < 4; ++r) {
            int lrow = wm + ti * 16 + quad * 4 + r;
            int cr = cRowS[lrow];
            if (cr < 0) continue;
            #pragma unroll
            for (int tj = 0; tj < 4; ++tj) {
                int nn = n0 + wn + tj * 16 + lm;
                float v = acc[ti][tj][r];
                if constexpr (MODE == SHARED_F32)
                    Cf[(size_t)cr * N + nn] = v;
                else if constexpr (MODE == GROUP_DENSE)
                    Cf[(size_t)cr * N + nn] = v * cWS[lrow];
                else
                    atomicAdd(&Cf[(size_t)cr * N + nn], v * cWS[lrow]);
            }
        }
    }
}

// ---------------- combine: out[t,:] += sum_k yexp[t*6+k,:] ----------------
__global__ __launch_bounds__(256) void combine_kernel(
    const float4* __restrict__ yexp, float4* __restrict__ out, int n4)
{
    const int D4 = DIMSZ / 4;   // 512
    int stride = gridDim.x * blockDim.x;
    for (int i = blockIdx.x * blockDim.x + threadIdx.x; i < n4; i += stride) {
        int t = i / D4, d4 = i - t * D4;
        const float4* r = yexp + (size_t)t * NTOPK * D4 + d4;
        float4 a = out[i];
        #pragma unroll
        for (int k = 0; k < NTOPK; ++k) {
            float4 s = r[(size_t)k * D4];
            a.x += s.x; a.y += s.y; a.z += s.z; a.w += s.w;
        }
        out[i] = a;
    }
}

extern "C" void kernel_launch(void* const* d_in, const int* in_sizes, int n_in,
                              void* d_out, int out_size, void* d_ws, size_t ws_size,
                              hipStream_t stream)
{
    const float* x   = (const float*)d_in[0];
    const float* gw  = (const float*)d_in[1];
    const float* w11 = (const float*)d_in[2];
    const float* w33 = (const float*)d_in[3];
    const float* w22 = (const float*)d_in[4];
    const float* sw1 = (const float*)d_in[5];
    const float* sw2 = (const float*)d_in[6];
    const float* sw3 = (const float*)d_in[7];
    float* out = (float*)d_out;

    char* ws = (char*)d_ws;
    size_t off = 0;
    auto alloc = [&](size_t b) { void* p = ws + off; off = (off + b + 255) & ~(size_t)255; return p; };
    int*            counts  = (int*)alloc(NEXP * 4);
    int*            toklist = (int*)alloc((size_t)NEXP * T_TOK * 4);
    float*          wgts    = (float*)alloc((size_t)NEXP * T_TOK * 4);
    float*          scores  = (float*)alloc((size_t)T_TOK * NEXP * 4);
    unsigned short* xb      = (unsigned short*)alloc((size_t)T_TOK * DIMSZ * 2);
    unsigned short* h       = (unsigned short*)alloc((size_t)T_TOK * NTOPK * INTERS * 2);
    unsigned short* hs      = (unsigned short*)alloc((size_t)T_TOK * SINTER * 2);

    // bf16 weight mirrors (fast path) -- only if workspace is large enough
    const size_t nW = (size_t)NEXP * INTERS * DIMSZ;   // 67.1M elems each of w11/w33/w22
    const size_t nS = (size_t)SINTER * DIMSZ;          // 4.19M elems each of sw1/sw3/sw2
    const size_t wbytes = 3 * (nW * 2) + 3 * (nS * 2) + 6 * 256;
    const bool WB = (off + wbytes) <= ws_size;
    unsigned short *w11b = nullptr, *w33b = nullptr, *w22b = nullptr;
    unsigned short *sw1b = nullptr, *sw3b = nullptr, *sw2b = nullptr;
    if (WB) {
        w11b = (unsigned short*)alloc(nW * 2);
        w33b = (unsigned short*)alloc(nW * 2);
        w22b = (unsigned short*)alloc(nW * 2);
        sw1b = (unsigned short*)alloc(nS * 2);
        sw3b = (unsigned short*)alloc(nS * 2);
        sw2b = (unsigned short*)alloc(nS * 2);
    }

    // dense fc2 output slots (allocated AFTER weights: WB has priority)
    const size_t yBytes = (size_t)T_TOK * NTOPK * DIMSZ * 4;   // 100.7 MB
    const bool DENSE = WB && (off + yBytes + 256) <= ws_size;
    float* yexp = nullptr;
    if (DENSE) yexp = (float*)alloc(yBytes);

    hipMemsetAsync(counts, 0, NEXP * 4, stream);

    int n4x = T_TOK * DIMSZ / 4;
    cvt_f2b<<<4096, 256, 0, stream>>>((const float4*)x, (ushort4*)xb, n4x);
    if (WB) {
        cvt_f2b<<<4096, 256, 0, stream>>>((const float4*)w11, (ushort4*)w11b, (int)(nW / 4));
        cvt_f2b<<<4096, 256, 0, stream>>>((const float4*)w33, (ushort4*)w33b, (int)(nW / 4));
        cvt_f2b<<<4096, 256, 0, stream>>>((const float4*)w22, (ushort4*)w22b, (int)(nW / 4));
        cvt_f2b<<<2048, 256, 0, stream>>>((const float4*)sw1, (ushort4*)sw1b, (int)(nS / 4));
        cvt_f2b<<<2048, 256, 0, stream>>>((const float4*)sw3, (ushort4*)sw3b, (int)(nS / 4));
        cvt_f2b<<<2048, 256, 0, stream>>>((const float4*)sw2, (ushort4*)sw2b, (int)(nS / 4));
    }

    gate_scores_kernel<<<T_TOK / SCT, 256, 0, stream>>>(x, gw, scores);
    topk_kernel<<<(T_TOK + 255) / 256, 256, 0, stream>>>(scores, counts, toklist, wgts);

    if (WB) {
        fc1_fused<false, true><<<dim3(SINTER / 128, T_TOK / 128, 1), 256, 0, stream>>>(
            xb, sw1b, sw3b, hs, SINTER, DIMSZ, T_TOK, nullptr, nullptr);
        gemm_bt<SHARED_F32, true><<<dim3(DIMSZ / 128, T_TOK / 128, 1), 256, 0, stream>>>(
            hs, sw2b, out, DIMSZ, SINTER, T_TOK, nullptr, nullptr, nullptr);
        fc1_fused<true, true><<<dim3(INTERS / 128, T_TOK / 128, NEXP), 256, 0, stream>>>(
            xb, w11b, w33b, h, INTERS, DIMSZ, 0, counts, toklist);
        if (DENSE) {
            gemm_bt<GROUP_DENSE, true><<<dim3(DIMSZ / 128, T_TOK / 128, NEXP), 256, 0, stream>>>(
                h, w22b, yexp, DIMSZ, INTERS, 0, counts, toklist, wgts);
            combine_kernel<<<2048, 256, 0, stream>>>((const float4*)yexp, (float4*)out, n4x);
        } else {
            gemm_bt<GROUP_FC2, true><<<dim3(DIMSZ / 128, T_TOK / 128, NEXP), 256, 0, stream>>>(
                h, w22b, out, DIMSZ, INTERS, 0, counts, toklist, wgts);
        }
    } else {
        fc1_fused<false, false><<<dim3(SINTER / 128, T_TOK / 128, 1), 256, 0, stream>>>(
            xb, sw1, sw3, hs, SINTER, DIMSZ, T_TOK, nullptr, nullptr);
        gemm_bt<SHARED_F32, false><<<dim3(DIMSZ / 128, T_TOK / 128, 1), 256, 0, stream>>>(
            hs, sw2, out, DIMSZ, SINTER, T_TOK, nullptr, nullptr, nullptr);
        fc1_fused<true, false><<<dim3(INTERS / 128, T_TOK / 128, NEXP), 256, 0, stream>>>(
            xb, w11, w33, h, INTERS, DIMSZ, 0, counts, toklist);
        gemm_bt<GROUP_FC2, false><<<dim3(DIMSZ / 128, T_TOK / 128, NEXP), 256, 0, stream>>>(
            h, w22, out, DIMSZ, INTERS, 0, counts, toklist, wgts);
    }
}